// Round 1
// baseline (140.087 us; speedup 1.0000x reference)
//
#include <hip/hip_runtime.h>

// Problem constants (from reference setup_inputs): bs=32, c=256, H=W=96
#define BS 32
#define CH 256
#define HH 96
#define WW 96
#define HW (HH * WW)        // 9216
#define HW4 (HW / 4)        // 2304 float4 per (b,c) plane

// Kernel A: proto[b*CH + c] = sum(feature[b,c,y1:y2,x1:x2]) / max((x2-x1)*(y2-y1), 1)
__global__ void proto_kernel(const float* __restrict__ feature,
                             const float* __restrict__ exemplars,
                             float* __restrict__ proto) {
    const int c = blockIdx.x;
    const int b = blockIdx.y;

    // Box bounds — replicate reference exactly: clip to [0,1], floor/ceil * dim
    const float x1f = fminf(fmaxf(exemplars[b * 4 + 0], 0.0f), 1.0f);
    const float y1f = fminf(fmaxf(exemplars[b * 4 + 1], 0.0f), 1.0f);
    const float x2f = fminf(fmaxf(exemplars[b * 4 + 2], 0.0f), 1.0f);
    const float y2f = fminf(fmaxf(exemplars[b * 4 + 3], 0.0f), 1.0f);
    const int x1 = (int)floorf(x1f * (float)WW);
    const int y1 = (int)floorf(y1f * (float)HH);
    const int x2 = (int)ceilf(x2f * (float)WW);
    const int y2 = (int)ceilf(y2f * (float)HH);

    const int bw = x2 - x1;
    const int bh = y2 - y1;
    const int npix = bw * bh;
    const float count = fmaxf((float)((x2 - x1) * (y2 - y1)), 1.0f);

    const float* base = feature + ((size_t)b * CH + c) * HW;

    float sum = 0.0f;
    for (int i = threadIdx.x; i < npix; i += blockDim.x) {
        const int yy = i / bw;          // bw >= 19 for valid boxes; npix==0 guards bw==0
        const int xx = i - yy * bw;
        sum += base[(y1 + yy) * WW + (x1 + xx)];
    }

    // wave64 butterfly-free down-shuffle reduce
    for (int off = 32; off > 0; off >>= 1)
        sum += __shfl_down(sum, off, 64);

    __shared__ float smem[4];
    const int lane = threadIdx.x & 63;
    const int wid  = threadIdx.x >> 6;
    if (lane == 0) smem[wid] = sum;
    __syncthreads();
    if (threadIdx.x == 0) {
        const float tot = smem[0] + smem[1] + smem[2] + smem[3];
        proto[b * CH + c] = tot / count;
    }
}

// Kernel B: out[i] = feature[i] * proto[plane(i)] * scale
__global__ void scale_kernel(const float4* __restrict__ f4,
                             const float* __restrict__ proto,
                             const float* __restrict__ scale,
                             float4* __restrict__ out4,
                             int n4) {
    const float s = scale[0];   // reference: / (1 + 1e-14) == /1.0f in fp32, then * scale
    const int stride = gridDim.x * blockDim.x;
    for (int i = blockIdx.x * blockDim.x + threadIdx.x; i < n4; i += stride) {
        const int plane = i / HW4;               // const divide -> magic mul
        const float p = proto[plane] * s;        // 32KB table, L1/L2-resident
        float4 v = f4[i];
        v.x *= p; v.y *= p; v.z *= p; v.w *= p;
        out4[i] = v;
    }
}

extern "C" void kernel_launch(void* const* d_in, const int* in_sizes, int n_in,
                              void* d_out, int out_size, void* d_ws, size_t ws_size,
                              hipStream_t stream) {
    const float* feature   = (const float*)d_in[0];
    const float* exemplars = (const float*)d_in[1];  // (bs,1,4) flat
    const float* scale     = (const float*)d_in[2];  // (1,)
    float* out   = (float*)d_out;
    float* proto = (float*)d_ws;                     // 8192 floats = 32 KB

    dim3 gridA(CH, BS);
    proto_kernel<<<gridA, 256, 0, stream>>>(feature, exemplars, proto);

    const int n4 = BS * CH * HW4;                    // 18,874,368
    scale_kernel<<<2048, 256, 0, stream>>>(
        (const float4*)feature, proto, scale, (float4*)out, n4);
}

// Round 2
// 120.774 us; speedup vs baseline: 1.1599x; 1.1599x over previous
//
#include <hip/hip_runtime.h>

// Problem constants (from reference setup_inputs): bs=32, c=256, H=W=96
#define BS 32
#define CH 256
#define HH 96
#define WW 96
#define HW (HH * WW)     // 9216 elements per (b,c) plane
#define HW4 (HW / 4)     // 2304 float4 per plane
#define W4 (WW / 4)      // 24 float4 per row (a float4 never spans rows)
#define NTHREADS 256
#define VPT (HW4 / NTHREADS)  // 9 float4 held per thread

// Fused: each block owns one (b,c) plane.
//   1) load plane into registers (exactly one HBM read)
//   2) box-masked sum in-register -> block reduce -> proto
//   3) scale held registers by proto*scale -> write out
__global__ __launch_bounds__(NTHREADS)
void fused_tm_kernel(const float4* __restrict__ f4,
                     const float* __restrict__ exemplars,
                     const float* __restrict__ scale,
                     float4* __restrict__ out4) {
    const int c = blockIdx.x;
    const int b = blockIdx.y;
    const size_t base4 = ((size_t)b * CH + c) * HW4;

    // Box bounds — replicate reference: clip to [0,1], floor/ceil * dim
    const float x1f = fminf(fmaxf(exemplars[b * 4 + 0], 0.0f), 1.0f);
    const float y1f = fminf(fmaxf(exemplars[b * 4 + 1], 0.0f), 1.0f);
    const float x2f = fminf(fmaxf(exemplars[b * 4 + 2], 0.0f), 1.0f);
    const float y2f = fminf(fmaxf(exemplars[b * 4 + 3], 0.0f), 1.0f);
    const int x1 = (int)floorf(x1f * (float)WW);
    const int y1 = (int)floorf(y1f * (float)HH);
    const int x2 = (int)ceilf(x2f * (float)WW);
    const int y2 = (int)ceilf(y2f * (float)HH);
    const float count = fmaxf((float)((x2 - x1) * (y2 - y1)), 1.0f);

    // 1) load + 2) masked sum
    float4 v[VPT];
    float sum = 0.0f;
#pragma unroll
    for (int j = 0; j < VPT; ++j) {
        const int p = threadIdx.x + j * NTHREADS;  // float4 index within plane
        v[j] = f4[base4 + p];
        const int y  = p / W4;             // const divide -> magic mul
        const int x0 = (p - y * W4) * 4;   // element x of v[j].x
        if (y >= y1 && y < y2) {
            sum += (x0     >= x1 && x0     < x2) ? v[j].x : 0.0f;
            sum += (x0 + 1 >= x1 && x0 + 1 < x2) ? v[j].y : 0.0f;
            sum += (x0 + 2 >= x1 && x0 + 2 < x2) ? v[j].z : 0.0f;
            sum += (x0 + 3 >= x1 && x0 + 3 < x2) ? v[j].w : 0.0f;
        }
    }

    // wave64 down-shuffle reduce
#pragma unroll
    for (int off = 32; off > 0; off >>= 1)
        sum += __shfl_down(sum, off, 64);

    __shared__ float smem[4];
    __shared__ float sproto;
    const int lane = threadIdx.x & 63;
    const int wid  = threadIdx.x >> 6;
    if (lane == 0) smem[wid] = sum;
    __syncthreads();
    if (threadIdx.x == 0) {
        // reference: proto = sum/count; out = f*proto/(1+1e-14)*scale; fp32 1+1e-14==1
        sproto = (smem[0] + smem[1] + smem[2] + smem[3]) / count * scale[0];
    }
    __syncthreads();
    const float p = sproto;

    // 3) scale held registers, write out
#pragma unroll
    for (int j = 0; j < VPT; ++j) {
        const int idx = threadIdx.x + j * NTHREADS;
        float4 t = v[j];
        t.x *= p; t.y *= p; t.z *= p; t.w *= p;
        out4[base4 + idx] = t;
    }
}

extern "C" void kernel_launch(void* const* d_in, const int* in_sizes, int n_in,
                              void* d_out, int out_size, void* d_ws, size_t ws_size,
                              hipStream_t stream) {
    const float* feature   = (const float*)d_in[0];
    const float* exemplars = (const float*)d_in[1];  // (bs,1,4) flat
    const float* scale     = (const float*)d_in[2];  // (1,)
    float* out = (float*)d_out;

    dim3 grid(CH, BS);  // one block per (b,c) plane
    fused_tm_kernel<<<grid, NTHREADS, 0, stream>>>(
        (const float4*)feature, exemplars, scale, (float4*)out);
}

// Round 4
// 100.586 us; speedup vs baseline: 1.3927x; 1.2007x over previous
//
#include <hip/hip_runtime.h>

// Problem constants (from reference setup_inputs): bs=32, c=256, H=W=96
#define BS 32
#define CH 256
#define HH 96
#define WW 96
#define HW (HH * WW)     // 9216 elements per (b,c) plane
#define HW4 (HW / 4)     // 2304 float4 per plane
#define W4 (WW / 4)      // 24 float4 per row (a float4 never spans rows)
#define NTHREADS 256
#define VPT (HW4 / NTHREADS)  // 9 float4 held per thread

// native clang vector type — __builtin_nontemporal_* requires this, not HIP float4
typedef float f32x4 __attribute__((ext_vector_type(4)));

// Fused: each block owns one (b,c) plane.
//   1) load plane into registers via nontemporal loads (exactly one HBM read)
//   2) box-masked sum in-register -> single-barrier block reduce -> proto
//   3) scale held registers by proto*scale -> nontemporal write out
__global__ __launch_bounds__(NTHREADS)
void fused_tm_kernel(const f32x4* __restrict__ f4,
                     const float* __restrict__ exemplars,
                     const float* __restrict__ scale,
                     f32x4* __restrict__ out4) {
    const int c = blockIdx.x;
    const int b = blockIdx.y;
    const size_t base4 = ((size_t)b * CH + c) * HW4;

    // Box bounds — replicate reference: clip to [0,1], floor/ceil * dim
    const float x1f = fminf(fmaxf(exemplars[b * 4 + 0], 0.0f), 1.0f);
    const float y1f = fminf(fmaxf(exemplars[b * 4 + 1], 0.0f), 1.0f);
    const float x2f = fminf(fmaxf(exemplars[b * 4 + 2], 0.0f), 1.0f);
    const float y2f = fminf(fmaxf(exemplars[b * 4 + 3], 0.0f), 1.0f);
    const int x1 = (int)floorf(x1f * (float)WW);
    const int y1 = (int)floorf(y1f * (float)HH);
    const int x2 = (int)ceilf(x2f * (float)WW);
    const int y2 = (int)ceilf(y2f * (float)HH);
    const float count = fmaxf((float)((x2 - x1) * (y2 - y1)), 1.0f);

    // 1) issue ALL loads first (9 dwordx4 in flight, single-touch -> nontemporal)
    f32x4 v[VPT];
#pragma unroll
    for (int j = 0; j < VPT; ++j)
        v[j] = __builtin_nontemporal_load(&f4[base4 + threadIdx.x + j * NTHREADS]);

    // 2) box-masked sum
    float sum = 0.0f;
#pragma unroll
    for (int j = 0; j < VPT; ++j) {
        const int p = threadIdx.x + j * NTHREADS;  // float4 index within plane
        const int y  = p / W4;             // const divide -> magic mul
        const int x0 = (p - y * W4) * 4;   // element x of v[j][0]
        if (y >= y1 && y < y2) {
            sum += (x0     >= x1 && x0     < x2) ? v[j][0] : 0.0f;
            sum += (x0 + 1 >= x1 && x0 + 1 < x2) ? v[j][1] : 0.0f;
            sum += (x0 + 2 >= x1 && x0 + 2 < x2) ? v[j][2] : 0.0f;
            sum += (x0 + 3 >= x1 && x0 + 3 < x2) ? v[j][3] : 0.0f;
        }
    }

    // wave64 down-shuffle reduce
#pragma unroll
    for (int off = 32; off > 0; off >>= 1)
        sum += __shfl_down(sum, off, 64);

    // single-barrier cross-wave reduce: every thread sums the 4 partials
    __shared__ float smem[4];
    const int lane = threadIdx.x & 63;
    const int wid  = threadIdx.x >> 6;
    if (lane == 0) smem[wid] = sum;
    __syncthreads();
    // reference: proto = sum/count; out = f*proto/(1+1e-14)*scale; fp32 1+1e-14==1
    const float p = (smem[0] + smem[1] + smem[2] + smem[3]) / count * scale[0];

    // 3) scale held registers, nontemporal write out
#pragma unroll
    for (int j = 0; j < VPT; ++j) {
        f32x4 t = v[j];
        t *= p;  // vector-scalar multiply on ext_vector_type
        __builtin_nontemporal_store(t, &out4[base4 + threadIdx.x + j * NTHREADS]);
    }
}

extern "C" void kernel_launch(void* const* d_in, const int* in_sizes, int n_in,
                              void* d_out, int out_size, void* d_ws, size_t ws_size,
                              hipStream_t stream) {
    const float* feature   = (const float*)d_in[0];
    const float* exemplars = (const float*)d_in[1];  // (bs,1,4) flat
    const float* scale     = (const float*)d_in[2];  // (1,)
    float* out = (float*)d_out;

    dim3 grid(CH, BS);  // one block per (b,c) plane
    fused_tm_kernel<<<grid, NTHREADS, 0, stream>>>(
        (const f32x4*)feature, exemplars, scale, (f32x4*)out);
}